// Round 11
// baseline (1807.280 us; speedup 1.0000x reference)
//
#include <hip/hip_runtime.h>

#define TT 512
#define BB 32
#define II 512
#define HH 1024
#define G3 3072
#define TBH (TT * BB * HH) /* 16777216 */

typedef __attribute__((ext_vector_type(8))) short short8;
typedef __attribute__((ext_vector_type(4))) float f32x4;

__device__ __forceinline__ float sigmoidf_(float x) {
    return 1.f / (1.f + __expf(-x));
}
__device__ __forceinline__ float tanh_fast(float x) {
    float e2 = __expf(2.f * x);
    return 1.f - 2.f / (e2 + 1.f);
}
/* round-to-nearest-even f32 -> bf16 (top 16 bits) */
__device__ __forceinline__ unsigned rne16(float x) {
    unsigned u = __float_as_uint(x);
    return (u + 0x7FFFu + ((u >> 16) & 1u)) >> 16;
}
/* split x = hi + lo (both bf16); |x - hi - lo| <= ~2^-18 |x|.
   For finite x, neither hi nor lo can be 0xFFFF (bf16 NaN) -> sentinel-safe. */
__device__ __forceinline__ void bsplit(float x, unsigned& hi, unsigned& lo) {
    unsigned h16 = rne16(x);
    float xh = __uint_as_float(h16 << 16);
    hi = h16;
    lo = rne16(x - xh); /* x - xh is exact */
}

/* ---- pre-split x into MFMA-frag-ordered bf16 hi/lo u64 planes ----
   xsplit u64 layout: [t 512][oct 4][wk 8]{ hi[128] | lo[128] } where the
   128 within-plane index = kf*64 + j*32 + kg*8 + cx, holding 4 bf16 of
   x[t][oct*8+cx][wk*64 + kf*32 + kg*8 + j*4 .. +3]. Matches k_persist's
   A-frag read: lane (kg,cx) reads (kf,j=0,1) pairs = 8 bf16 in k-order. */
__global__ __launch_bounds__(256) void k_split_x(const float* __restrict__ x,
                                                 unsigned long long* __restrict__ xsplit) {
    int g = blockIdx.x * 256 + threadIdx.x; /* 2,097,152 = 512t x 32b x 128q */
    int t = g >> 12;
    int r = g & 4095;
    int b = r >> 7, q = r & 127;
    float4 s = *(const float4*)(x + ((size_t)t * 32 + b) * 512 + q * 4);
    unsigned h0, l0, h1, l1, h2, l2, h3, l3;
    bsplit(s.x, h0, l0);
    bsplit(s.y, h1, l1);
    bsplit(s.z, h2, l2);
    bsplit(s.w, h3, l3);
    unsigned long long hq = (unsigned long long)(h0 | (h1 << 16)) |
                            ((unsigned long long)(h2 | (h3 << 16)) << 32);
    unsigned long long lq = (unsigned long long)(l0 | (l1 << 16)) |
                            ((unsigned long long)(l2 | (l3 << 16)) << 32);
    int oct = b >> 3, cx = b & 7;
    int wk = q >> 4, kf = (q >> 3) & 1, kg = (q >> 1) & 3, j = q & 1;
    size_t base = (((size_t)t * 4 + oct) * 8 + wk) * 256;
    size_t w_ = (size_t)(kf * 64 + j * 32 + kg * 8 + cx);
    xsplit[base + w_] = hq;
    xsplit[base + 128 + w_] = lq;
}

/* ---- persistent recurrent kernel, v11 = v10 + NONTEMPORAL out stores ----
   ONE isolated change vs v10: the two out[] stores use
   __builtin_nontemporal_store. Rationale: out streams 128MB/launch
   through L3, evicting hstage sentinel lines (64MB, L3-resident after
   the 0xFF memset). Once evicted, the producer's 8B agent store
   write-allocate-misses -> fetches the sentinel line from HBM (~900cy)
   before the line is consumer-visible — on the serial recurrence, every
   step (the ~150-250MB unexplained FETCH). nt stores bypass L3
   allocation so hstage stays resident: store->visible and poll-hit both
   become ~L3 latency. Falsifiable signature: FETCH drops ~100-150MB;
   WRITE/conflicts unchanged.
   Everything else (v8/v5 2-barrier exchange — R9 proved the loop-end
   barrier is a poll rate-limiter; fused gi on pre-split x frags) is
   byte-identical to v10. */
__global__ __launch_bounds__(512, 2) void k_persist(const float* __restrict__ w_hh,
                                                    const float* __restrict__ w_ih,
                                                    const float* __restrict__ pad,
                                                    const float* __restrict__ b_ih,
                                                    const float* __restrict__ b_hh,
                                                    float* __restrict__ out,
                                                    unsigned long long* __restrict__ hstage,
                                                    const unsigned long long* __restrict__ xsplit,
                                                    int t0, int ct) {
    __shared__ float part[8 * 768]; /* [wave][g*192 + col*12 + b] , g=0..3 */

    int tid = threadIdx.x;
    int hg = blockIdx.x & 63, boct = blockIdx.x >> 6;
    int hc0 = hg << 4;
    int b0 = boct << 3;

    int wk = tid >> 6;  /* wave id: h k-slice [wk*128,+128), x k-slice [wk*64,+64) */
    int lane = tid & 63;
    int kg = lane >> 4; /* k-group within frag */
    int cx = lane & 15; /* A-row (batch) / C-col */

    /* ---- one-time: W_hh -> bf16 hi/lo frags (96 VGPRs) ---- */
    short8 Bh[3][4], Bl[3][4];
#pragma unroll
    for (int g = 0; g < 3; ++g)
#pragma unroll
        for (int kf = 0; kf < 4; ++kf) {
            unsigned hh_[8], ll_[8];
#pragma unroll
            for (int j = 0; j < 8; ++j) {
                int k = wk * 128 + kf * 32 + kg * 8 + j;
                float w = w_hh[(size_t)k * G3 + hc0 + cx + g * HH];
                bsplit(w, hh_[j], ll_[j]);
            }
            union { unsigned u[4]; short8 s; } ph, pl;
#pragma unroll
            for (int r = 0; r < 4; ++r) {
                ph.u[r] = hh_[2 * r] | (hh_[2 * r + 1] << 16);
                pl.u[r] = ll_[2 * r] | (ll_[2 * r + 1] << 16);
            }
            Bh[g][kf] = ph.s;
            Bl[g][kf] = pl.s;
        }
    /* ---- one-time: W_ih -> bf16 hi/lo frags (48 VGPRs) ---- */
    short8 Ih[3][2], Il[3][2];
#pragma unroll
    for (int g = 0; g < 3; ++g)
#pragma unroll
        for (int kf = 0; kf < 2; ++kf) {
            unsigned hh_[8], ll_[8];
#pragma unroll
            for (int j = 0; j < 8; ++j) {
                int k = wk * 64 + kf * 32 + kg * 8 + j;
                float w = w_ih[(size_t)k * G3 + hc0 + cx + g * HH];
                bsplit(w, hh_[j], ll_[j]);
            }
            union { unsigned u[4]; short8 s; } ph, pl;
#pragma unroll
            for (int r = 0; r < 4; ++r) {
                ph.u[r] = hh_[2 * r] | (hh_[2 * r + 1] << 16);
                pl.u[r] = ll_[2 * r] | (ll_[2 * r + 1] << 16);
            }
            Ih[g][kf] = ph.s;
            Il[g][kf] = pl.s;
        }

    /* gate-thread constants (tid<128: col = hc0+cg, batch = b2) */
    int cg = tid & 15, b2 = tid >> 4;
    int col = hc0 + cg;
    int bg = b0 + b2;
    float cR = 0.f, cZ = 0.f, bin = 0.f, bhn = 0.f, hprev = 0.f;
    if (tid < 128) {
        cR = b_ih[col] + b_hh[col];
        cZ = b_ih[col + HH] + b_hh[col + HH];
        bin = b_ih[col + 2 * HH];
        bhn = b_hh[col + 2 * HH];
        if (t0 > 0)
            hprev = out[(size_t)(t0 - 1) * (BB * HH) + (size_t)bg * HH + col];
    }

    /* producer staging address: col -> (kf,j,kg) slot in frag order */
    int co = ((hg & 7) << 4) | cg; /* k-offset within my wk-slice, 0..127 */
    size_t sbase_p = (size_t)boct * 2097152 + (size_t)(hg >> 3) * 512 +
                     (size_t)((co >> 5) * 64 + ((co >> 2) & 1) * 32 +
                              ((co >> 3) & 3) * 8 + b2);
    /* consumer base: lane (kg,cx<8) reads 16 u64s at +plane*256+kf*64+j*32 */
    size_t cbase = (size_t)boct * 2097152 + (size_t)wk * 512 + (size_t)(kg * 8 + cx);

    for (int s = 0; s < ct; ++s) {
        int t = t0 + s;

        /* pad prefetch */
        float pv = 0.f;
        if (tid < 128) pv = pad[t * BB + bg];

        /* ---- x A-frags: plain loads from pre-split planes (no polling);
           issued BEFORE the poll so they complete under the spin ---- */
        unsigned long long xv[8];
        if (cx < 8) {
            const unsigned long long* xp =
                xsplit + ((((size_t)t * 4 + boct) * 8 + wk) << 8);
            int off = kg * 8 + cx;
#pragma unroll
            for (int kf = 0; kf < 2; ++kf)
#pragma unroll
                for (int j = 0; j < 2; ++j) {
                    xv[kf * 2 + j] = xp[kf * 64 + j * 32 + off];
                    xv[4 + kf * 2 + j] = xp[128 + kf * 64 + j * 32 + off];
                }
        } else {
#pragma unroll
            for (int i = 0; i < 8; ++i) xv[i] = 0ull;
        }

        /* ---- h A-frags: poll-load packed staging of h(t-1) ---- */
        unsigned long long v[16];
        if (t > 0 && cx < 8) {
            const unsigned long long* sp = hstage + cbase + (size_t)(t - 1) * 4096;
#pragma unroll
            for (int i = 0; i < 16; ++i)
                v[i] = __hip_atomic_load(sp + (i >> 3) * 256 + ((i >> 1) & 3) * 64 +
                                             (i & 1) * 32,
                                         __ATOMIC_RELAXED, __HIP_MEMORY_SCOPE_AGENT);
            for (;;) {
                int bad = 0;
#pragma unroll
                for (int i = 0; i < 16; ++i)
                    if ((unsigned)v[i] == 0xFFFFFFFFu ||
                        (unsigned)(v[i] >> 32) == 0xFFFFFFFFu)
                        bad |= 1 << i;
                if (!bad) break;
#pragma unroll
                for (int i = 0; i < 16; ++i)
                    if (bad & (1 << i))
                        v[i] = __hip_atomic_load(sp + (i >> 3) * 256 +
                                                     ((i >> 1) & 3) * 64 + (i & 1) * 32,
                                                 __ATOMIC_RELAXED,
                                                 __HIP_MEMORY_SCOPE_AGENT);
            }
        } else {
#pragma unroll
            for (int i = 0; i < 16; ++i) v[i] = 0ull;
        }

        /* MFMA: acc planes 0=r(x+h), 1=z(x+h), 2=n_x, 3=n_h */
        f32x4 acc[4];
        acc[0] = (f32x4){0.f, 0.f, 0.f, 0.f};
        acc[1] = (f32x4){0.f, 0.f, 0.f, 0.f};
        acc[2] = (f32x4){0.f, 0.f, 0.f, 0.f};
        acc[3] = (f32x4){0.f, 0.f, 0.f, 0.f};
        /* x part: 2 kf x 3 gates x 3 = 18 MFMA */
#pragma unroll
        for (int kf = 0; kf < 2; ++kf) {
            union { unsigned long long q[2]; short8 s8; } uh, ul;
            uh.q[0] = xv[kf * 2];
            uh.q[1] = xv[kf * 2 + 1];
            ul.q[0] = xv[4 + kf * 2];
            ul.q[1] = xv[4 + kf * 2 + 1];
#pragma unroll
            for (int g = 0; g < 3; ++g) {
                int tg = g; /* gate 2 (n) x-part -> acc[2] */
                acc[tg] = __builtin_amdgcn_mfma_f32_16x16x32_bf16(uh.s8, Ih[g][kf], acc[tg], 0, 0, 0);
                acc[tg] = __builtin_amdgcn_mfma_f32_16x16x32_bf16(uh.s8, Il[g][kf], acc[tg], 0, 0, 0);
                acc[tg] = __builtin_amdgcn_mfma_f32_16x16x32_bf16(ul.s8, Ih[g][kf], acc[tg], 0, 0, 0);
            }
        }
        /* h part: 4 kf x 3 gates x 3 = 36 MFMA */
#pragma unroll
        for (int kf = 0; kf < 4; ++kf) {
            union { unsigned long long q[2]; short8 s8; } uh, ul;
            uh.q[0] = v[kf * 2];
            uh.q[1] = v[kf * 2 + 1];
            ul.q[0] = v[8 + kf * 2];
            ul.q[1] = v[8 + kf * 2 + 1];
#pragma unroll
            for (int g = 0; g < 3; ++g) {
                int tg = (g == 2) ? 3 : g; /* gate 2 (n) h-part -> acc[3] */
                acc[tg] = __builtin_amdgcn_mfma_f32_16x16x32_bf16(uh.s8, Bh[g][kf], acc[tg], 0, 0, 0);
                acc[tg] = __builtin_amdgcn_mfma_f32_16x16x32_bf16(uh.s8, Bl[g][kf], acc[tg], 0, 0, 0);
                acc[tg] = __builtin_amdgcn_mfma_f32_16x16x32_bf16(ul.s8, Bh[g][kf], acc[tg], 0, 0, 0);
            }
        }
        /* partial C: lanes 0..31 hold valid batch rows 0..7 */
        if (lane < 32) {
            int r0 = (lane >> 4) * 4;
#pragma unroll
            for (int g = 0; g < 4; ++g)
                *(f32x4*)&part[wk * 768 + g * 192 + cx * 12 + r0] = acc[g];
        }
        __syncthreads();

        /* gates: 128 threads reduce 8 wave-partials per (g,b,col) */
        if (tid < 128) {
            float gh0 = 0.f, gh1 = 0.f, gh2 = 0.f, gh3 = 0.f;
#pragma unroll
            for (int w = 0; w < 8; ++w) {
                int base = w * 768 + cg * 12 + b2;
                gh0 += part[base];
                gh1 += part[base + 192];
                gh2 += part[base + 384];
                gh3 += part[base + 576];
            }
            float r = sigmoidf_(gh0 + cR);
            float z = sigmoidf_(gh1 + cZ);
            float n = tanh_fast(gh2 + bin + r * (gh3 + bhn));
            float hnew = (1.f - z) * n + z * hprev;
            hnew = pv * hprev + (1.f - pv) * hnew;
            hprev = hnew; /* exact f32 carried to next step */

            /* stage FIRST: split, pair-pack via 4-lane shuffles */
            unsigned hi_, lo_;
            bsplit(hnew, hi_, lo_);
            unsigned hiA = hi_ | (((unsigned)__shfl_xor((int)hi_, 1)) << 16);
            unsigned loA = lo_ | (((unsigned)__shfl_xor((int)lo_, 1)) << 16);
            unsigned hiB = (unsigned)__shfl_xor((int)hiA, 2);
            unsigned loB = (unsigned)__shfl_xor((int)loA, 2);
            if ((cg & 3) == 0) {
                unsigned long long hq =
                    (unsigned long long)hiA | ((unsigned long long)hiB << 32);
                unsigned long long lq =
                    (unsigned long long)loA | ((unsigned long long)loB << 32);
                unsigned long long* dst = hstage + sbase_p + (size_t)t * 4096;
                __hip_atomic_store(dst, hq, __ATOMIC_RELAXED,
                                   __HIP_MEMORY_SCOPE_AGENT);
                __hip_atomic_store(dst + 256, lq, __ATOMIC_RELAXED,
                                   __HIP_MEMORY_SCOPE_AGENT);
            }
            /* nontemporal: keep the 128MB out stream from evicting hstage
               out of L3 (out is write-only in-kernel) */
            size_t oo = (size_t)t * (BB * HH) + (size_t)bg * HH + col;
            __builtin_nontemporal_store(hnew, out + oo);
            __builtin_nontemporal_store(hnew, out + (size_t)TBH + oo);
        }
        /* WAR guard + poll rate-limiter (R9: do NOT remove) */
        __syncthreads();
    }
}

/* ---- emergency fallback if workspace is tiny: fused, slow, correct ---- */
__global__ __launch_bounds__(256) void k_step_slow(const float* __restrict__ x_t,
                                                   const float* __restrict__ pad_t,
                                                   const float* __restrict__ w_ih,
                                                   const float* __restrict__ w_hh,
                                                   const float* __restrict__ b_ih,
                                                   const float* __restrict__ b_hh,
                                                   const float* __restrict__ h_in,
                                                   float* __restrict__ h_out,
                                                   float* __restrict__ out, int t) {
    int g = blockIdx.x * 256 + threadIdx.x;
    int b = g >> 10, j = g & 1023;
    float gir = b_ih[j], giz = b_ih[j + HH], gin = b_ih[j + 2 * HH];
    for (int k = 0; k < II; ++k) {
        float xv = x_t[b * II + k];
        const float* wr = w_ih + (size_t)k * G3;
        gir += xv * wr[j];
        giz += xv * wr[j + HH];
        gin += xv * wr[j + 2 * HH];
    }
    float ghr = b_hh[j], ghz = b_hh[j + HH], ghn = b_hh[j + 2 * HH];
    for (int k = 0; k < HH; ++k) {
        float hv = h_in[b * HH + k];
        const float* wr = w_hh + (size_t)k * G3;
        ghr += hv * wr[j];
        ghz += hv * wr[j + HH];
        ghn += hv * wr[j + 2 * HH];
    }
    float hprev = h_in[b * HH + j];
    float p = pad_t[b];
    float r = sigmoidf_(gir + ghr);
    float z = sigmoidf_(giz + ghz);
    float n = tanh_fast(gin + r * ghn);
    float hnew = (1.f - z) * n + z * hprev;
    hnew = p * hprev + (1.f - p) * hnew;
    size_t o = (size_t)b * HH + j;
    h_out[o] = hnew;
    size_t oo = (size_t)t * (BB * HH) + o;
    out[oo] = hnew;
    out[(size_t)TBH + oo] = hnew;
}

extern "C" void kernel_launch(void* const* d_in, const int* in_sizes, int n_in,
                              void* d_out, int out_size, void* d_ws, size_t ws_size,
                              hipStream_t stream) {
    const float* x    = (const float*)d_in[0];
    const float* pad  = (const float*)d_in[1];
    const float* w_ih = (const float*)d_in[2];
    const float* w_hh = (const float*)d_in[3];
    const float* b_ih = (const float*)d_in[4];
    const float* b_hh = (const float*)d_in[5];
    float* out = (float*)d_out;

    char* wsb = (char*)d_ws;
    float* hA = (float*)wsb;            /* 128 KB (fallback only) */
    float* hB = (float*)(wsb + 131072); /* 128 KB (fallback only) */
    unsigned long long* hstage = (unsigned long long*)(wsb + 262144);   /* 64 MB */
    unsigned long long* xsplit = (unsigned long long*)(wsb + 67371008); /* 33.5 MB */
    /* end of xsplit = 67371008 + 33554432 = 100925440 */

    if (ws_size >= 100925440ULL) {
        k_split_x<<<8192, 256, 0, stream>>>(x, xsplit);
        hipMemsetAsync(hstage, 0xFF, 67108864, stream); /* bf16 NaN sentinel */
        k_persist<<<256, 512, 0, stream>>>(w_hh, w_ih, pad, b_ih, b_hh, out,
                                           hstage, xsplit, 0, TT);
    } else {
        hipMemsetAsync(hA, 0, 131072, stream); /* h(t=0) = 0 */
        for (int t = 0; t < TT; ++t) {
            const float* hin = (t & 1) ? hB : hA;
            float* hout = (t & 1) ? hA : hB;
            k_step_slow<<<128, 256, 0, stream>>>(x + (size_t)t * BB * II, pad + t * BB,
                                                 w_ih, w_hh, b_ih, b_hh, hin, hout, out, t);
        }
    }
}